// Round 9
// baseline (187.512 us; speedup 1.0000x reference)
//
#include <hip/hip_runtime.h>
#include <hip/hip_bf16.h>
#include <cstdint>
#include <cstddef>

// RBF Gram matrix: K[i,j] = exp(-gamma * ||a_i - b_j||^2), A,B: [8192,256] f32.
// Out: [8192,8192] f32.
//
// ROUND-9 PROBE: R7's best structure (87.5us) + R8's verified folded epilogue,
// with the GEMM body executed TWICE inside one dispatch (identical output both
// passes). Purpose: the harness's 1-GiB fill dispatches (~155us) occupy all
// top-5 rocprof slots, so the ~85us GEMM has never shown counters. Doubling
// the dispatch to ~170us surfaces MfmaUtil / VALUBusy / OccupancyPercent /
// SQ_LDS_BANK_CONFLICT / FETCH+WRITE for the GEMM itself. Next round reverts
// to single-pass and applies the indicated fix.

#define GAMMA_F 0.00390625f
#define LOG2E_F 1.44269504088896340736f

typedef __attribute__((ext_vector_type(8))) short short8;   // 8 bf16
typedef __attribute__((ext_vector_type(4))) float f32x4;    // acc / 16B

constexpr int KD = 256;
constexpr int ND = 8192;
constexpr int BM = 128, BN = 128, BK = 32;
constexpr int TPB = 4;     // tiles per block (consecutive tile-cols)
constexpr int NKT = KD / BK;
constexpr int NREP = 2;    // PROBE: run GEMM body twice in one dispatch

__device__ __forceinline__ unsigned short f2b(float f) {
  unsigned int u = __float_as_uint(f);
  u += 0x7FFFu + ((u >> 16) & 1u);
  return (unsigned short)(u >> 16);
}

__device__ __forceinline__ void gload_lds16(const void* g, void* l) {
  __builtin_amdgcn_global_load_lds(
      (const __attribute__((address_space(1))) unsigned int*)g,
      (__attribute__((address_space(3))) unsigned int*)l, 16, 0, 0);
}

// ---------------------------------------------------------------------------
// Prepass: pre-scaled row norms n = -gamma*log2e*||row||^2 + bf16 convert.
// ---------------------------------------------------------------------------
__global__ __launch_bounds__(256) void norm_convert_kernel(
    const float* __restrict__ A, const float* __restrict__ B,
    unsigned short* Abf, unsigned short* Bbf,
    float* __restrict__ na, float* __restrict__ nb)
{
  const int lane = threadIdx.x & 63;
  const int row = blockIdx.x * 4 + (threadIdx.x >> 6);
  const float* src = A;
  unsigned short* dst = Abf;
  float* nrm = na;
  int r = row;
  if (row >= ND) { src = B; dst = Bbf; nrm = nb; r = row - ND; }

  const float4 v = *(const float4*)(src + (size_t)r * KD + lane * 4);
  float s = v.x * v.x + v.y * v.y + v.z * v.z + v.w * v.w;
  #pragma unroll
  for (int off = 32; off >= 1; off >>= 1) s += __shfl_xor(s, off, 64);

  if (dst) {
    const unsigned int p0 = (unsigned)f2b(v.x) | ((unsigned)f2b(v.y) << 16);
    const unsigned int p1 = (unsigned)f2b(v.z) | ((unsigned)f2b(v.w) << 16);
    *(uint2*)(dst + (size_t)r * KD + lane * 4) = make_uint2(p0, p1);
  }
  if (lane == 0) nrm[r] = -GAMMA_F * LOG2E_F * s;
}

// ---------------------------------------------------------------------------
// Main GEMM + RBF epilogue: R7 structure exactly (2-phase dbuf via
// __syncthreads, 4 waves 2x2, acc[4][4], TPB=4 tile walk, swapped-operand
// MFMA, staging involution f(b)=b^(((b>>7)&3)<<4) on global source + ds_read).
// ---------------------------------------------------------------------------
template <bool BF16WS>
__global__ __launch_bounds__(256) void rbf_gemm_kernel(
    const void* __restrict__ Aop, const void* __restrict__ Bop,
    const float* __restrict__ na, const float* __restrict__ nb,
    float* __restrict__ C)
{
  __shared__ __align__(16) char smem[32768];
  const int t = threadIdx.x;
  const int lane = t & 63;
  const int wid = t >> 6;
  const int wm = wid >> 1, wn = wid & 1;

  // XCD mapping (bijective, 8 XCDs x 128 blocks).
  const int bid = blockIdx.x;
  const int x = bid & 7;
  const int k = bid >> 3;
  const int tr = ((x >> 1) << 4) + (k >> 3);   // tile row 0..63
  const int tcq = ((x & 1) << 3) + (k & 7);    // tile quad 0..15
  const int brow = tr << 7;
  const int tc0 = tcq << 2;

  const int srow = t >> 2;
  const int scolb = (((t & 3) ^ ((t >> 3) & 3)) << 4);

  int aoff[4], boff[4];
  #pragma unroll
  for (int f = 0; f < 4; ++f) {
    const int ra = wm * 64 + f * 16 + (lane & 15);
    aoff[f] = ra * 64 + (((lane >> 4) * 16) ^ (((ra >> 1) & 3) << 4));
    const int rb = wn * 64 + f * 16 + (lane & 15);
    boff[f] = 16384 + rb * 64 + (((lane >> 4) * 16) ^ (((rb >> 1) & 3) << 4));
  }

  const char* Ab = (const char*)Aop;
  const char* Bb = (const char*)Bop;
  const float* Af = (const float*)Aop;
  const float* Bf = (const float*)Bop;
  const float c2 = 2.0f * GAMMA_F * LOG2E_F;

  auto stage = [&](int buf, int kt, int bcol) {
    if constexpr (BF16WS) {
      #pragma unroll
      for (int h = 0; h < 2; ++h) {
        gload_lds16(Ab + (size_t)(brow + h * 64 + srow) * (KD * 2) + kt * (BK * 2) + scolb,
                    smem + buf * 8192 + h * 4096 + wid * 1024);
        gload_lds16(Bb + (size_t)(bcol + h * 64 + srow) * (KD * 2) + kt * (BK * 2) + scolb,
                    smem + 16384 + buf * 8192 + h * 4096 + wid * 1024);
      }
    } else {
      #pragma unroll
      for (int h = 0; h < 2; ++h) {
        const float* sa = Af + (size_t)(brow + h * 64 + srow) * KD + kt * BK + (scolb >> 1);
        const float4 a0 = *(const float4*)sa;
        const float4 a1 = *(const float4*)(sa + 4);
        *(uint4*)(smem + buf * 8192 + h * 4096 + t * 16) = make_uint4(
            (unsigned)f2b(a0.x) | ((unsigned)f2b(a0.y) << 16),
            (unsigned)f2b(a0.z) | ((unsigned)f2b(a0.w) << 16),
            (unsigned)f2b(a1.x) | ((unsigned)f2b(a1.y) << 16),
            (unsigned)f2b(a1.z) | ((unsigned)f2b(a1.w) << 16));
        const float* sb = Bf + (size_t)(bcol + h * 64 + srow) * KD + kt * BK + (scolb >> 1);
        const float4 b0 = *(const float4*)sb;
        const float4 b1 = *(const float4*)(sb + 4);
        *(uint4*)(smem + 16384 + buf * 8192 + h * 4096 + t * 16) = make_uint4(
            (unsigned)f2b(b0.x) | ((unsigned)f2b(b0.y) << 16),
            (unsigned)f2b(b0.z) | ((unsigned)f2b(b0.w) << 16),
            (unsigned)f2b(b1.x) | ((unsigned)f2b(b1.y) << 16),
            (unsigned)f2b(b1.z) | ((unsigned)f2b(b1.w) << 16));
      }
    }
  };

  for (int rep = 0; rep < NREP; ++rep) {
    // ---- prologue: stage tile 0 / K-step 0 ----
    stage(0, 0, tc0 << 7);
    __syncthreads();

    for (int t4 = 0; t4 < TPB; ++t4) {
      const int bcol = (tc0 + t4) << 7;
      f32x4 acc[4][4] = {};

      for (int kt = 0; kt < NKT; ++kt) {
        const int cur = kt & 1;
        if (kt + 1 < NKT) stage(cur ^ 1, kt + 1, bcol);

        const int cb = cur * 8192;
        short8 af[4], bfv[4];
        #pragma unroll
        for (int f = 0; f < 4; ++f) {
          af[f]  = *(const short8*)(smem + cb + aoff[f]);
          bfv[f] = *(const short8*)(smem + cb + boff[f]);
        }
        // Swapped operands: thread holds C[i][j0..j0+3].
        #pragma unroll
        for (int fm = 0; fm < 4; ++fm)
          #pragma unroll
          for (int fn = 0; fn < 4; ++fn)
            acc[fm][fn] = __builtin_amdgcn_mfma_f32_16x16x32_bf16(
                bfv[fn], af[fm], acc[fm][fn], 0, 0, 0);

        __syncthreads();
      }

      // ---- prefetch next tile's first K-step (hidden by epilogue) ----
      if (t4 + 1 < TPB) stage(0, 0, (tc0 + t4 + 1) << 7);

      // ---- folded epilogue: exp2(na + nb + c2*dot), plain f32x4 stores ----
      #pragma unroll
      for (int fm = 0; fm < 4; ++fm) {
        const int i = brow + wm * 64 + fm * 16 + (lane & 15);
        const float an = na[i];
        float* crow = C + (size_t)i * ND;
        #pragma unroll
        for (int fn = 0; fn < 4; ++fn) {
          const int j0 = bcol + wn * 64 + fn * 16 + ((lane >> 4) << 2);
          const f32x4 b4 = *(const f32x4*)&nb[j0];
          f32x4 o;
          o[0] = exp2f(fmaf(c2, acc[fm][fn][0], an + b4[0]));
          o[1] = exp2f(fmaf(c2, acc[fm][fn][1], an + b4[1]));
          o[2] = exp2f(fmaf(c2, acc[fm][fn][2], an + b4[2]));
          o[3] = exp2f(fmaf(c2, acc[fm][fn][3], an + b4[3]));
          *(f32x4*)&crow[j0] = o;
        }
      }

      if (t4 + 1 < TPB) __syncthreads();
    }
    if (rep + 1 < NREP) __syncthreads();   // protect LDS before next rep
  }
}

// ---------------------------------------------------------------------------
extern "C" void kernel_launch(void* const* d_in, const int* in_sizes, int n_in,
                              void* d_out, int out_size, void* d_ws, size_t ws_size,
                              hipStream_t stream) {
  const float* A = (const float*)d_in[0];
  const float* B = (const float*)d_in[1];
  float* C = (float*)d_out;

  const size_t bfBytes = (size_t)ND * KD * 2;   // 4 MiB per matrix
  const size_t normBytes = (size_t)ND * 4;
  char* ws = (char*)d_ws;
  const int grid = (ND / BM) * (ND / BN) / TPB;  // 1024

  if (ws_size >= 2 * bfBytes + 2 * normBytes) {
    unsigned short* Abf = (unsigned short*)ws;
    unsigned short* Bbf = (unsigned short*)(ws + bfBytes);
    float* na = (float*)(ws + 2 * bfBytes);
    float* nb = (float*)(ws + 2 * bfBytes + normBytes);
    hipLaunchKernelGGL(norm_convert_kernel, dim3(2 * ND / 4), dim3(256), 0, stream,
                       A, B, Abf, Bbf, na, nb);
    hipLaunchKernelGGL((rbf_gemm_kernel<true>), dim3(grid), dim3(256), 0,
                       stream, (const void*)Abf, (const void*)Bbf, na, nb, C);
  } else {
    float* na = (float*)ws;
    float* nb = (float*)(ws + normBytes);
    hipLaunchKernelGGL(norm_convert_kernel, dim3(2 * ND / 4), dim3(256), 0, stream,
                       A, B, (unsigned short*)nullptr, (unsigned short*)nullptr, na, nb);
    hipLaunchKernelGGL((rbf_gemm_kernel<false>), dim3(grid), dim3(256), 0,
                       stream, (const void*)A, (const void*)B, na, nb, C);
  }
}

// Round 10
// 85.919 us; speedup vs baseline: 2.1824x; 2.1824x over previous
//
#include <hip/hip_runtime.h>
#include <hip/hip_bf16.h>
#include <cstdint>
#include <cstddef>

// RBF Gram matrix: K[i,j] = exp(-gamma * ||a_i - b_j||^2), A,B: [8192,256] f32.
// Out: [8192,8192] f32.
//
// Round-10: counters (R9 probe) showed MfmaUtil 15% / VALUBusy 24% / 0 bank
// conflicts / write pipe half idle -> 60% of cycles stalled on the 2-phase
// stage->drain->barrier critical path (the m233 pathology). Fix: 256x256 tile,
// 8 waves, BK=32, TRIPLE-buffered LDS (96KB) with counted vmcnt(4) boundaries
// (T4: loads stay in flight a full K-step; never drain to 0 in-loop), 2 phases
// per K-step with raw s_barrier, s_setprio around MFMA (T5). Stores only at
// kernel end (no store/load vmcnt mixing - R8's failure). Staging involution
// f(b)=b^(((b>>7)&3)<<4) unchanged (verified: SQ_LDS_BANK_CONFLICT=0).

#define GAMMA_F 0.00390625f
#define LOG2E_F 1.44269504088896340736f

typedef __attribute__((ext_vector_type(8))) short short8;   // 8 bf16
typedef __attribute__((ext_vector_type(4))) float f32x4;    // acc / 16B

constexpr int KD = 256;
constexpr int ND = 8192;
constexpr int NKT = KD / 32;   // 8 K-steps of BK=32

__device__ __forceinline__ unsigned short f2b(float f) {
  unsigned int u = __float_as_uint(f);
  u += 0x7FFFu + ((u >> 16) & 1u);
  return (unsigned short)(u >> 16);
}

__device__ __forceinline__ void gload_lds16(const void* g, void* l) {
  __builtin_amdgcn_global_load_lds(
      (const __attribute__((address_space(1))) unsigned int*)g,
      (__attribute__((address_space(3))) unsigned int*)l, 16, 0, 0);
}

#define FULL_BARRIER() do { asm volatile("" ::: "memory"); \
  __builtin_amdgcn_s_barrier(); asm volatile("" ::: "memory"); } while (0)

// ---------------------------------------------------------------------------
// Prepass: pre-scaled row norms n = -gamma*log2e*||row||^2 + bf16 convert.
// ---------------------------------------------------------------------------
__global__ __launch_bounds__(256) void norm_convert_kernel(
    const float* __restrict__ A, const float* __restrict__ B,
    unsigned short* Abf, unsigned short* Bbf,
    float* __restrict__ na, float* __restrict__ nb)
{
  const int lane = threadIdx.x & 63;
  const int row = blockIdx.x * 4 + (threadIdx.x >> 6);
  const float* src = A;
  unsigned short* dst = Abf;
  float* nrm = na;
  int r = row;
  if (row >= ND) { src = B; dst = Bbf; nrm = nb; r = row - ND; }

  const float4 v = *(const float4*)(src + (size_t)r * KD + lane * 4);
  float s = v.x * v.x + v.y * v.y + v.z * v.z + v.w * v.w;
  #pragma unroll
  for (int off = 32; off >= 1; off >>= 1) s += __shfl_xor(s, off, 64);

  if (dst) {
    const unsigned int p0 = (unsigned)f2b(v.x) | ((unsigned)f2b(v.y) << 16);
    const unsigned int p1 = (unsigned)f2b(v.z) | ((unsigned)f2b(v.w) << 16);
    *(uint2*)(dst + (size_t)r * KD + lane * 4) = make_uint2(p0, p1);
  }
  if (lane == 0) nrm[r] = -GAMMA_F * LOG2E_F * s;
}

// ---------------------------------------------------------------------------
// Main 256x256 GEMM + RBF epilogue. 512 threads = 8 waves (2M x 4N); wave
// owns 128x64 of C: acc[8][4] 16x16 fragments. LDS: 3 bufs x (A[256][64B] +
// B[256][64B]) = 96KB. Buf b: A @ b*32768, B @ b*32768+16384.
//
// Pipeline (T3+T4): step k phase0 stages step k+2 into buf (k+2)%3 (4
// gload_lds16/thread); boundary of step k waits vmcnt(4) (step k+1's 4 loads
// were issued a full step earlier -> forced complete; step k+2's 4 newest
// stay in flight). vmcnt never drains to 0 in the steady loop.
// ---------------------------------------------------------------------------
__global__ __launch_bounds__(512, 2) void rbf_gemm256_kernel(
    const unsigned short* __restrict__ Abf, const unsigned short* __restrict__ Bbf,
    const float* __restrict__ na, const float* __restrict__ nb,
    float* __restrict__ C)
{
  __shared__ __align__(16) char smem[98304];
  const int t = threadIdx.x;
  const int lane = t & 63;
  const int wid = t >> 6;          // 0..7
  const int wm = wid >> 2;         // 0..1  (M half)
  const int wn = wid & 3;          // 0..3  (N quarter)

  // XCD mapping (bijective, 8 x 128 on the 32x32 tile grid): XCD x owns an
  // 8-tile-row x 16-tile-col region.
  const int bid = blockIdx.x;
  const int x = bid & 7;
  const int k = bid >> 3;                       // 0..127
  const int tr = ((x >> 1) << 3) + (k >> 4);    // 0..31
  const int tc = ((x & 1) << 4) + (k & 15);     // 0..31
  const int brow = tr << 8;
  const int bcol = tc << 8;

  // Staging: dest (implicit) = chunkbase + t*16 -> row r = g*128 + t>>2,
  // col byte c = (t&3)<<4; source col swizzled by involution
  // f: c' = c ^ (((r>>1)&3)<<4)  =>  scolb = ((t&3)^((t>>3)&3))<<4.
  const int srow = t >> 2;                                   // 0..127
  const int scolb = (((t & 3) ^ ((t >> 3) & 3)) << 4);

  // Fragment ds_read byte offsets (within a buf; add bufbase at use).
  int aoff[8], boff[4];
  #pragma unroll
  for (int fm = 0; fm < 8; ++fm) {
    const int r = wm * 128 + fm * 16 + (lane & 15);
    aoff[fm] = r * 64 + ((((lane >> 4)) ^ ((r >> 1) & 3)) << 4);
  }
  #pragma unroll
  for (int fn = 0; fn < 4; ++fn) {
    const int r = wn * 64 + fn * 16 + (lane & 15);
    boff[fn] = 16384 + r * 64 + ((((lane >> 4)) ^ ((r >> 1) & 3)) << 4);
  }

  const char* Ab = (const char*)Abf;
  const char* Bb = (const char*)Bbf;

  auto stageAB = [&](int buf, int kt) {
    const int g0 = buf * 32768;
    #pragma unroll
    for (int g = 0; g < 2; ++g) {
      gload_lds16(Ab + (size_t)(brow + g * 128 + srow) * 512 + kt * 64 + scolb,
                  smem + g0 + g * 8192 + (wid << 10));
      gload_lds16(Bb + (size_t)(bcol + g * 128 + srow) * 512 + kt * 64 + scolb,
                  smem + g0 + 16384 + g * 8192 + (wid << 10));
    }
  };

  f32x4 acc[8][4] = {};

  // ---- prologue: 2 steps staged; wait only for step 0 (vmcnt(4)) ----
  stageAB(0, 0);
  stageAB(1, 1);
  asm volatile("s_waitcnt vmcnt(4)" ::: "memory");
  FULL_BARRIER();

  #pragma unroll
  for (int kt = 0; kt < NKT; ++kt) {
    const int cb = (kt % 3) * 32768;

    // ---- phase 0: B frags + A frags 0-3, stage kt+2, 16 MFMA ----
    short8 bf_[4], af_[4];
    #pragma unroll
    for (int fn = 0; fn < 4; ++fn) bf_[fn] = *(const short8*)(smem + cb + boff[fn]);
    #pragma unroll
    for (int fm = 0; fm < 4; ++fm) af_[fm] = *(const short8*)(smem + cb + aoff[fm]);
    if (kt + 2 < NKT) stageAB((kt + 2) % 3, kt + 2);

    __builtin_amdgcn_s_setprio(1);
    #pragma unroll
    for (int fm = 0; fm < 4; ++fm)
      #pragma unroll
      for (int fn = 0; fn < 4; ++fn)
        acc[fm][fn] = __builtin_amdgcn_mfma_f32_16x16x32_bf16(
            bf_[fn], af_[fm], acc[fm][fn], 0, 0, 0);
    __builtin_amdgcn_s_setprio(0);
    FULL_BARRIER();

    // ---- phase 1: A frags 4-7, 16 MFMA ----
    short8 ag_[4];
    #pragma unroll
    for (int fm = 0; fm < 4; ++fm) ag_[fm] = *(const short8*)(smem + cb + aoff[fm + 4]);

    __builtin_amdgcn_s_setprio(1);
    #pragma unroll
    for (int fm = 0; fm < 4; ++fm)
      #pragma unroll
      for (int fn = 0; fn < 4; ++fn)
        acc[fm + 4][fn] = __builtin_amdgcn_mfma_f32_16x16x32_bf16(
            bf_[fn], ag_[fm], acc[fm + 4][fn], 0, 0, 0);
    __builtin_amdgcn_s_setprio(0);

    // ---- boundary: counted wait (never 0 while stages remain) ----
    if (kt < NKT - 1) {
      if (kt + 2 < NKT) { asm volatile("s_waitcnt vmcnt(4)" ::: "memory"); }
      else              { asm volatile("s_waitcnt vmcnt(0)" ::: "memory"); }
      FULL_BARRIER();
    }
  }

  // ---- epilogue: K = exp2(na + nb + 2*gamma*log2e*dot); f32x4 stores ----
  const float c2 = 2.0f * GAMMA_F * LOG2E_F;
  #pragma unroll
  for (int fm = 0; fm < 8; ++fm) {
    const int i = brow + wm * 128 + fm * 16 + (lane & 15);
    const float an = na[i];
    float* crow = C + (size_t)i * ND;
    #pragma unroll
    for (int fn = 0; fn < 4; ++fn) {
      const int j0 = bcol + wn * 64 + fn * 16 + ((lane >> 4) << 2);
      const f32x4 b4 = *(const f32x4*)&nb[j0];
      f32x4 o;
      o[0] = exp2f(fmaf(c2, acc[fm][fn][0], an + b4[0]));
      o[1] = exp2f(fmaf(c2, acc[fm][fn][1], an + b4[1]));
      o[2] = exp2f(fmaf(c2, acc[fm][fn][2], an + b4[2]));
      o[3] = exp2f(fmaf(c2, acc[fm][fn][3], an + b4[3]));
      *(f32x4*)&crow[j0] = o;
    }
  }
}

// ---------------------------------------------------------------------------
// Fallback (tiny d_ws): R7-style 128x128 serial kernel, f32->bf16 inline.
// ---------------------------------------------------------------------------
__global__ __launch_bounds__(256) void rbf_gemm_fallback(
    const float* __restrict__ Af, const float* __restrict__ Bf,
    const float* __restrict__ na, const float* __restrict__ nb,
    float* __restrict__ C)
{
  __shared__ __align__(16) char smem[16384];
  const int t = threadIdx.x;
  const int lane = t & 63;
  const int wid = t >> 6;
  const int wm = wid >> 1, wn = wid & 1;
  const int bid = blockIdx.x;
  const int brow = (bid >> 6) << 7;
  const int bcol = (bid & 63) << 7;
  const int srow = t >> 2;
  const int scolb = (((t & 3) ^ ((t >> 3) & 3)) << 4);

  int aoff[4], boff[4];
  #pragma unroll
  for (int f = 0; f < 4; ++f) {
    const int ra = wm * 64 + f * 16 + (lane & 15);
    aoff[f] = ra * 64 + (((lane >> 4) * 16) ^ (((ra >> 1) & 3) << 4));
    const int rb = wn * 64 + f * 16 + (lane & 15);
    boff[f] = 8192 + rb * 64 + (((lane >> 4) * 16) ^ (((rb >> 1) & 3) << 4));
  }

  f32x4 acc[4][4] = {};
  for (int kt = 0; kt < 8; ++kt) {
    #pragma unroll
    for (int h = 0; h < 2; ++h) {
      const float* sa = Af + (size_t)(brow + h * 64 + srow) * KD + kt * 32 + (scolb >> 1);
      const float4 a0 = *(const float4*)sa;
      const float4 a1 = *(const float4*)(sa + 4);
      *(uint4*)(smem + h * 4096 + t * 16) = make_uint4(
          (unsigned)f2b(a0.x) | ((unsigned)f2b(a0.y) << 16),
          (unsigned)f2b(a0.z) | ((unsigned)f2b(a0.w) << 16),
          (unsigned)f2b(a1.x) | ((unsigned)f2b(a1.y) << 16),
          (unsigned)f2b(a1.z) | ((unsigned)f2b(a1.w) << 16));
      const float* sb = Bf + (size_t)(bcol + h * 64 + srow) * KD + kt * 32 + (scolb >> 1);
      const float4 b0 = *(const float4*)sb;
      const float4 b1 = *(const float4*)(sb + 4);
      *(uint4*)(smem + 8192 + h * 4096 + t * 16) = make_uint4(
          (unsigned)f2b(b0.x) | ((unsigned)f2b(b0.y) << 16),
          (unsigned)f2b(b0.z) | ((unsigned)f2b(b0.w) << 16),
          (unsigned)f2b(b1.x) | ((unsigned)f2b(b1.y) << 16),
          (unsigned)f2b(b1.z) | ((unsigned)f2b(b1.w) << 16));
    }
    __syncthreads();
    short8 af[4], bfv[4];
    #pragma unroll
    for (int f = 0; f < 4; ++f) {
      af[f]  = *(const short8*)(smem + aoff[f]);
      bfv[f] = *(const short8*)(smem + boff[f]);
    }
    #pragma unroll
    for (int fm = 0; fm < 4; ++fm)
      #pragma unroll
      for (int fn = 0; fn < 4; ++fn)
        acc[fm][fn] = __builtin_amdgcn_mfma_f32_16x16x32_bf16(
            bfv[fn], af[fm], acc[fm][fn], 0, 0, 0);
    __syncthreads();
  }

  const float c2 = 2.0f * GAMMA_F * LOG2E_F;
  #pragma unroll
  for (int fm = 0; fm < 4; ++fm) {
    const int i = brow + wm * 64 + fm * 16 + (lane & 15);
    const float an = na[i];
    float* crow = C + (size_t)i * ND;
    #pragma unroll
    for (int fn = 0; fn < 4; ++fn) {
      const int j0 = bcol + wn * 64 + fn * 16 + ((lane >> 4) << 2);
      const f32x4 b4 = *(const f32x4*)&nb[j0];
      f32x4 o;
      o[0] = exp2f(fmaf(c2, acc[fm][fn][0], an + b4[0]));
      o[1] = exp2f(fmaf(c2, acc[fm][fn][1], an + b4[1]));
      o[2] = exp2f(fmaf(c2, acc[fm][fn][2], an + b4[2]));
      o[3] = exp2f(fmaf(c2, acc[fm][fn][3], an + b4[3]));
      *(f32x4*)&crow[j0] = o;
    }
  }
}

// ---------------------------------------------------------------------------
extern "C" void kernel_launch(void* const* d_in, const int* in_sizes, int n_in,
                              void* d_out, int out_size, void* d_ws, size_t ws_size,
                              hipStream_t stream) {
  const float* A = (const float*)d_in[0];
  const float* B = (const float*)d_in[1];
  float* C = (float*)d_out;

  const size_t bfBytes = (size_t)ND * KD * 2;   // 4 MiB per matrix
  const size_t normBytes = (size_t)ND * 4;
  char* ws = (char*)d_ws;

  if (ws_size >= 2 * bfBytes + 2 * normBytes) {
    unsigned short* Abf = (unsigned short*)ws;
    unsigned short* Bbf = (unsigned short*)(ws + bfBytes);
    float* na = (float*)(ws + 2 * bfBytes);
    float* nb = (float*)(ws + 2 * bfBytes + normBytes);
    hipLaunchKernelGGL(norm_convert_kernel, dim3(2 * ND / 4), dim3(256), 0, stream,
                       A, B, Abf, Bbf, na, nb);
    hipLaunchKernelGGL(rbf_gemm256_kernel, dim3((ND / 256) * (ND / 256)), dim3(512), 0,
                       stream, Abf, Bbf, na, nb, C);
  } else {
    float* na = (float*)ws;
    float* nb = (float*)(ws + normBytes);
    hipLaunchKernelGGL(norm_convert_kernel, dim3(2 * ND / 4), dim3(256), 0, stream,
                       A, B, (unsigned short*)nullptr, (unsigned short*)nullptr, na, nb);
    hipLaunchKernelGGL(rbf_gemm_fallback, dim3((ND / 128) * (ND / 128)), dim3(256), 0,
                       stream, A, B, na, nb, C);
  }
}

// Round 11
// 85.827 us; speedup vs baseline: 2.1848x; 1.0011x over previous
//
#include <hip/hip_runtime.h>
#include <hip/hip_bf16.h>
#include <cstdint>
#include <cstddef>

// RBF Gram matrix: K[i,j] = exp(-gamma * ||a_i - b_j||^2), A,B: [8192,256] f32.
// Out: [8192,8192] f32.
//
// Round-11: R10's counted-vmcnt triple-buffer schedule (T4) on R7's 128x128
// multi-block geometry. R10 proved the pipeline but its 96KB LDS forced
// 1 block/CU -> fully serial K-loop/epilogue/store-drain per CU (measured:
// write pipe 2.8 TB/s, never saturated; MFMA at floor ratio). Now: 48KB LDS
// (3 bufs x 16KB), 3 blocks/CU co-resident, 16 blocks/CU queued -> one
// block's exp2+store drain overlaps the others' K-loops; stores spread
// across the whole kernel. Counted vmcnt(4) boundaries (never 0 in-loop),
// raw s_barrier, setprio around MFMA. Staging involution + swapped-operand
// MFMA + folded epilogue unchanged (all verified; bank conflicts = 0).

#define GAMMA_F 0.00390625f
#define LOG2E_F 1.44269504088896340736f

typedef __attribute__((ext_vector_type(8))) short short8;   // 8 bf16
typedef __attribute__((ext_vector_type(4))) float f32x4;    // acc / 16B

constexpr int KD = 256;
constexpr int ND = 8192;
constexpr int NKT = KD / 32;   // 8 K-steps of BK=32

__device__ __forceinline__ unsigned short f2b(float f) {
  unsigned int u = __float_as_uint(f);
  u += 0x7FFFu + ((u >> 16) & 1u);
  return (unsigned short)(u >> 16);
}

__device__ __forceinline__ void gload_lds16(const void* g, void* l) {
  __builtin_amdgcn_global_load_lds(
      (const __attribute__((address_space(1))) unsigned int*)g,
      (__attribute__((address_space(3))) unsigned int*)l, 16, 0, 0);
}

#define FULL_BARRIER() do { asm volatile("" ::: "memory"); \
  __builtin_amdgcn_s_barrier(); asm volatile("" ::: "memory"); } while (0)

// ---------------------------------------------------------------------------
// Prepass: pre-scaled row norms n = -gamma*log2e*||row||^2 + bf16 convert.
// ---------------------------------------------------------------------------
__global__ __launch_bounds__(256) void norm_convert_kernel(
    const float* __restrict__ A, const float* __restrict__ B,
    unsigned short* Abf, unsigned short* Bbf,
    float* __restrict__ na, float* __restrict__ nb)
{
  const int lane = threadIdx.x & 63;
  const int row = blockIdx.x * 4 + (threadIdx.x >> 6);
  const float* src = A;
  unsigned short* dst = Abf;
  float* nrm = na;
  int r = row;
  if (row >= ND) { src = B; dst = Bbf; nrm = nb; r = row - ND; }

  const float4 v = *(const float4*)(src + (size_t)r * KD + lane * 4);
  float s = v.x * v.x + v.y * v.y + v.z * v.z + v.w * v.w;
  #pragma unroll
  for (int off = 32; off >= 1; off >>= 1) s += __shfl_xor(s, off, 64);

  if (dst) {
    const unsigned int p0 = (unsigned)f2b(v.x) | ((unsigned)f2b(v.y) << 16);
    const unsigned int p1 = (unsigned)f2b(v.z) | ((unsigned)f2b(v.w) << 16);
    *(uint2*)(dst + (size_t)r * KD + lane * 4) = make_uint2(p0, p1);
  }
  if (lane == 0) nrm[r] = -GAMMA_F * LOG2E_F * s;
}

// ---------------------------------------------------------------------------
// Main 128x128 GEMM + RBF epilogue. 256 threads = 4 waves (2x2); wave owns
// 64x64 (acc[4][4]). LDS: 3 bufs x (A[128][64B] + B[128][64B]) = 48KB ->
// 3 blocks/CU. Buf b: A @ b*16384, B @ b*16384+8192.
//
// Pipeline (T4): step k reads buf k%3, stages step k+2 into buf (k+2)%3
// (4 gload_lds16/thread), boundary waits vmcnt(4) -> step k+1's 4 loads
// (issued a full step earlier) complete; step k+2's 4 stay in flight.
// Safety: buf (k+2)%3 == buf (k-1)%3, whose readers consumed their ds_reads
// (MFMA lgkmcnt) before the barrier that opened step k.
// ---------------------------------------------------------------------------
__global__ __launch_bounds__(256, 3) void rbf_gemm_kernel(
    const unsigned short* __restrict__ Abf, const unsigned short* __restrict__ Bbf,
    const float* __restrict__ na, const float* __restrict__ nb,
    float* __restrict__ C)
{
  __shared__ __align__(16) char smem[49152];
  const int t = threadIdx.x;
  const int lane = t & 63;
  const int wid = t >> 6;
  const int wm = wid >> 1, wn = wid & 1;

  // XCD mapping (bijective, 8 XCDs x 512): 16x32-tile region per XCD ->
  // ~2MB B-panel + 1MB A-panel resident in the XCD L2.
  const int bid = blockIdx.x;
  const int x = bid & 7;
  const int k = bid >> 3;
  const int tr = ((x >> 1) << 4) + (k >> 5);   // tile row 0..63
  const int tc = ((x & 1) << 5) + (k & 31);    // tile col 0..63
  const int brow = tr << 7;
  const int bcol = tc << 7;

  // Staging: linear dest chunk + t*16; GLOBAL source col swizzled by the
  // involution f(b)=b^(((b>>7)&3)<<4) -> scolb = ((t&3)^((t>>3)&3))<<4.
  const int srow = t >> 2;                                   // 0..63
  const int scolb = (((t & 3) ^ ((t >> 3) & 3)) << 4);

  // Fragment ds_read offsets (within buf; add buf*16384 at use).
  int aoff[4], boff[4];
  #pragma unroll
  for (int f = 0; f < 4; ++f) {
    const int ra = wm * 64 + f * 16 + (lane & 15);
    aoff[f] = ra * 64 + (((lane >> 4) * 16) ^ (((ra >> 1) & 3) << 4));
    const int rb = wn * 64 + f * 16 + (lane & 15);
    boff[f] = 8192 + rb * 64 + (((lane >> 4) * 16) ^ (((rb >> 1) & 3) << 4));
  }

  const char* Ab = (const char*)Abf;
  const char* Bb = (const char*)Bbf;

  auto stage = [&](int buf, int kt) {
    #pragma unroll
    for (int h = 0; h < 2; ++h) {
      gload_lds16(Ab + (size_t)(brow + h * 64 + srow) * 512 + kt * 64 + scolb,
                  smem + buf * 16384 + h * 4096 + (wid << 10));
      gload_lds16(Bb + (size_t)(bcol + h * 64 + srow) * 512 + kt * 64 + scolb,
                  smem + buf * 16384 + 8192 + h * 4096 + (wid << 10));
    }
  };

  f32x4 acc[4][4] = {};

  // ---- prologue: 2 steps staged; wait only for step 0 ----
  stage(0, 0);
  stage(1, 1);
  asm volatile("s_waitcnt vmcnt(4)" ::: "memory");
  FULL_BARRIER();

  #pragma unroll
  for (int kt = 0; kt < NKT; ++kt) {
    const int cb = (kt % 3) * 16384;

    short8 af[4], bfv[4];
    #pragma unroll
    for (int f = 0; f < 4; ++f) {
      af[f]  = *(const short8*)(smem + cb + aoff[f]);
      bfv[f] = *(const short8*)(smem + cb + boff[f]);
    }
    if (kt + 2 < NKT) stage((kt + 2) % 3, kt + 2);

    __builtin_amdgcn_s_setprio(1);
    // Swapped operands: thread holds C[i][j0..j0+3].
    #pragma unroll
    for (int fm = 0; fm < 4; ++fm)
      #pragma unroll
      for (int fn = 0; fn < 4; ++fn)
        acc[fm][fn] = __builtin_amdgcn_mfma_f32_16x16x32_bf16(
            bfv[fn], af[fm], acc[fm][fn], 0, 0, 0);
    __builtin_amdgcn_s_setprio(0);

    if (kt < NKT - 1) {
      if (kt + 2 < NKT) { asm volatile("s_waitcnt vmcnt(4)" ::: "memory"); }
      else              { asm volatile("s_waitcnt vmcnt(0)" ::: "memory"); }
      FULL_BARRIER();
    }
  }

  // ---- folded epilogue: K = exp2(na + nb + 2*gamma*log2e*dot) ----
  const float c2 = 2.0f * GAMMA_F * LOG2E_F;
  #pragma unroll
  for (int fm = 0; fm < 4; ++fm) {
    const int i = brow + wm * 64 + fm * 16 + (lane & 15);
    const float an = na[i];
    float* crow = C + (size_t)i * ND;
    #pragma unroll
    for (int fn = 0; fn < 4; ++fn) {
      const int j0 = bcol + wn * 64 + fn * 16 + ((lane >> 4) << 2);
      const f32x4 b4 = *(const f32x4*)&nb[j0];
      f32x4 o;
      o[0] = exp2f(fmaf(c2, acc[fm][fn][0], an + b4[0]));
      o[1] = exp2f(fmaf(c2, acc[fm][fn][1], an + b4[1]));
      o[2] = exp2f(fmaf(c2, acc[fm][fn][2], an + b4[2]));
      o[3] = exp2f(fmaf(c2, acc[fm][fn][3], an + b4[3]));
      *(f32x4*)&crow[j0] = o;
    }
  }
}

// ---------------------------------------------------------------------------
// Fallback (tiny d_ws): 128x128 serial kernel, f32->bf16 inline.
// ---------------------------------------------------------------------------
__global__ __launch_bounds__(256) void rbf_gemm_fallback(
    const float* __restrict__ Af, const float* __restrict__ Bf,
    const float* __restrict__ na, const float* __restrict__ nb,
    float* __restrict__ C)
{
  __shared__ __align__(16) char smem[16384];
  const int t = threadIdx.x;
  const int lane = t & 63;
  const int wid = t >> 6;
  const int wm = wid >> 1, wn = wid & 1;
  const int bid = blockIdx.x;
  const int brow = (bid >> 6) << 7;
  const int bcol = (bid & 63) << 7;
  const int srow = t >> 2;
  const int scolb = (((t & 3) ^ ((t >> 3) & 3)) << 4);

  int aoff[4], boff[4];
  #pragma unroll
  for (int f = 0; f < 4; ++f) {
    const int ra = wm * 64 + f * 16 + (lane & 15);
    aoff[f] = ra * 64 + (((lane >> 4) * 16) ^ (((ra >> 1) & 3) << 4));
    const int rb = wn * 64 + f * 16 + (lane & 15);
    boff[f] = 8192 + rb * 64 + (((lane >> 4) * 16) ^ (((rb >> 1) & 3) << 4));
  }

  f32x4 acc[4][4] = {};
  for (int kt = 0; kt < 8; ++kt) {
    #pragma unroll
    for (int h = 0; h < 2; ++h) {
      const float* sa = Af + (size_t)(brow + h * 64 + srow) * KD + kt * 32 + (scolb >> 1);
      const float4 a0 = *(const float4*)sa;
      const float4 a1 = *(const float4*)(sa + 4);
      *(uint4*)(smem + h * 4096 + t * 16) = make_uint4(
          (unsigned)f2b(a0.x) | ((unsigned)f2b(a0.y) << 16),
          (unsigned)f2b(a0.z) | ((unsigned)f2b(a0.w) << 16),
          (unsigned)f2b(a1.x) | ((unsigned)f2b(a1.y) << 16),
          (unsigned)f2b(a1.z) | ((unsigned)f2b(a1.w) << 16));
      const float* sb = Bf + (size_t)(bcol + h * 64 + srow) * KD + kt * 32 + (scolb >> 1);
      const float4 b0 = *(const float4*)sb;
      const float4 b1 = *(const float4*)(sb + 4);
      *(uint4*)(smem + 8192 + h * 4096 + t * 16) = make_uint4(
          (unsigned)f2b(b0.x) | ((unsigned)f2b(b0.y) << 16),
          (unsigned)f2b(b0.z) | ((unsigned)f2b(b0.w) << 16),
          (unsigned)f2b(b1.x) | ((unsigned)f2b(b1.y) << 16),
          (unsigned)f2b(b1.z) | ((unsigned)f2b(b1.w) << 16));
    }
    __syncthreads();
    short8 af[4], bfv[4];
    #pragma unroll
    for (int f = 0; f < 4; ++f) {
      af[f]  = *(const short8*)(smem + aoff[f]);
      bfv[f] = *(const short8*)(smem + boff[f]);
    }
    #pragma unroll
    for (int fm = 0; fm < 4; ++fm)
      #pragma unroll
      for (int fn = 0; fn < 4; ++fn)
        acc[fm][fn] = __builtin_amdgcn_mfma_f32_16x16x32_bf16(
            bfv[fn], af[fm], acc[fm][fn], 0, 0, 0);
    __syncthreads();
  }

  const float c2 = 2.0f * GAMMA_F * LOG2E_F;
  #pragma unroll
  for (int fm = 0; fm < 4; ++fm) {
    const int i = brow + wm * 64 + fm * 16 + (lane & 15);
    const float an = na[i];
    float* crow = C + (size_t)i * ND;
    #pragma unroll
    for (int fn = 0; fn < 4; ++fn) {
      const int j0 = bcol + wn * 64 + fn * 16 + ((lane >> 4) << 2);
      const f32x4 b4 = *(const f32x4*)&nb[j0];
      f32x4 o;
      o[0] = exp2f(fmaf(c2, acc[fm][fn][0], an + b4[0]));
      o[1] = exp2f(fmaf(c2, acc[fm][fn][1], an + b4[1]));
      o[2] = exp2f(fmaf(c2, acc[fm][fn][2], an + b4[2]));
      o[3] = exp2f(fmaf(c2, acc[fm][fn][3], an + b4[3]));
      *(f32x4*)&crow[j0] = o;
    }
  }
}

// ---------------------------------------------------------------------------
extern "C" void kernel_launch(void* const* d_in, const int* in_sizes, int n_in,
                              void* d_out, int out_size, void* d_ws, size_t ws_size,
                              hipStream_t stream) {
  const float* A = (const float*)d_in[0];
  const float* B = (const float*)d_in[1];
  float* C = (float*)d_out;

  const size_t bfBytes = (size_t)ND * KD * 2;   // 4 MiB per matrix
  const size_t normBytes = (size_t)ND * 4;
  char* ws = (char*)d_ws;

  if (ws_size >= 2 * bfBytes + 2 * normBytes) {
    unsigned short* Abf = (unsigned short*)ws;
    unsigned short* Bbf = (unsigned short*)(ws + bfBytes);
    float* na = (float*)(ws + 2 * bfBytes);
    float* nb = (float*)(ws + 2 * bfBytes + normBytes);
    hipLaunchKernelGGL(norm_convert_kernel, dim3(2 * ND / 4), dim3(256), 0, stream,
                       A, B, Abf, Bbf, na, nb);
    hipLaunchKernelGGL(rbf_gemm_kernel, dim3((ND / 128) * (ND / 128)), dim3(256), 0,
                       stream, Abf, Bbf, na, nb, C);
  } else {
    float* na = (float*)ws;
    float* nb = (float*)(ws + normBytes);
    hipLaunchKernelGGL(norm_convert_kernel, dim3(2 * ND / 4), dim3(256), 0, stream,
                       A, B, (unsigned short*)nullptr, (unsigned short*)nullptr, na, nb);
    hipLaunchKernelGGL(rbf_gemm_fallback, dim3((ND / 128) * (ND / 128)), dim3(256), 0,
                       stream, A, B, na, nb, C);
  }
}

// Round 12
// 85.635 us; speedup vs baseline: 2.1897x; 1.0022x over previous
//
#include <hip/hip_runtime.h>
#include <hip/hip_bf16.h>
#include <cstdint>
#include <cstddef>

// RBF Gram matrix: K[i,j] = exp(-gamma * ||a_i - b_j||^2), A,B: [8192,256] f32.
// Out: [8192,8192] f32.
//
// Round-12: cross-tile software-pipelined epilogue. R7/R8/R10/R11 all land at
// 86-94us with no pipe >45% busy: the wall is the SERIAL per-block chain
// K-loop -> exp burst -> store burst (lockstepped across co-resident blocks,
// so cross-block overlap never materializes). Fix inside program order: each
// block walks 4 tiles; tile t's accumulator is parked in pacc[] and its 16
// fragment-epilogues (exp2 + f32x4 store) are executed 2-per-K-step inside
// tile t+1's K-loop, between the MFMA cluster and the barrier. Stores/exp2
// issue continuously instead of in end-bursts. Verified pieces unchanged:
// staging involution f(b)=b^(((b>>7)&3)<<4) (bank conflicts = 0), swapped-
// operand MFMA, folded epilogue math, XCD 16x32-tile regions.

#define GAMMA_F 0.00390625f
#define LOG2E_F 1.44269504088896340736f

typedef __attribute__((ext_vector_type(8))) short short8;   // 8 bf16
typedef __attribute__((ext_vector_type(4))) float f32x4;    // acc / 16B

constexpr int KD = 256;
constexpr int ND = 8192;
constexpr int NKT = KD / 32;   // 8 K-steps of BK=32
constexpr int TPB = 4;         // tiles per block (consecutive tile-cols)

__device__ __forceinline__ unsigned short f2b(float f) {
  unsigned int u = __float_as_uint(f);
  u += 0x7FFFu + ((u >> 16) & 1u);
  return (unsigned short)(u >> 16);
}

__device__ __forceinline__ void gload_lds16(const void* g, void* l) {
  __builtin_amdgcn_global_load_lds(
      (const __attribute__((address_space(1))) unsigned int*)g,
      (__attribute__((address_space(3))) unsigned int*)l, 16, 0, 0);
}

// ---------------------------------------------------------------------------
// Prepass: pre-scaled row norms n = -gamma*log2e*||row||^2 + bf16 convert.
// ---------------------------------------------------------------------------
__global__ __launch_bounds__(256) void norm_convert_kernel(
    const float* __restrict__ A, const float* __restrict__ B,
    unsigned short* Abf, unsigned short* Bbf,
    float* __restrict__ na, float* __restrict__ nb)
{
  const int lane = threadIdx.x & 63;
  const int row = blockIdx.x * 4 + (threadIdx.x >> 6);
  const float* src = A;
  unsigned short* dst = Abf;
  float* nrm = na;
  int r = row;
  if (row >= ND) { src = B; dst = Bbf; nrm = nb; r = row - ND; }

  const float4 v = *(const float4*)(src + (size_t)r * KD + lane * 4);
  float s = v.x * v.x + v.y * v.y + v.z * v.z + v.w * v.w;
  #pragma unroll
  for (int off = 32; off >= 1; off >>= 1) s += __shfl_xor(s, off, 64);

  if (dst) {
    const unsigned int p0 = (unsigned)f2b(v.x) | ((unsigned)f2b(v.y) << 16);
    const unsigned int p1 = (unsigned)f2b(v.z) | ((unsigned)f2b(v.w) << 16);
    *(uint2*)(dst + (size_t)r * KD + lane * 4) = make_uint2(p0, p1);
  }
  if (lane == 0) nrm[r] = -GAMMA_F * LOG2E_F * s;
}

// ---------------------------------------------------------------------------
// Main 128x128 GEMM + pipelined RBF epilogue. 256 threads = 4 waves (2x2);
// wave owns 64x64 (acc[4][4]). LDS: 2 bufs x 16KB = 32KB. Fully unrolled
// 32-step (4 tiles x 8 K-steps) chain; buffer = global-step parity.
// ---------------------------------------------------------------------------
__global__ __launch_bounds__(256, 2) void rbf_gemm_kernel(
    const unsigned short* __restrict__ Abf, const unsigned short* __restrict__ Bbf,
    const float* __restrict__ na, const float* __restrict__ nb,
    float* __restrict__ C)
{
  __shared__ __align__(16) char smem[32768];
  const int t = threadIdx.x;
  const int lane = t & 63;
  const int wid = t >> 6;
  const int wm = wid >> 1, wn = wid & 1;

  // XCD mapping (bijective, 8 XCDs x 128 blocks): 16-tile-row x 8-tile-quad
  // region per XCD -> ~2MB B + 1MB A panels resident in the XCD L2.
  const int bid = blockIdx.x;
  const int x = bid & 7;
  const int k = bid >> 3;
  const int tr = ((x >> 1) << 4) + (k >> 3);   // tile row 0..63
  const int tcq = ((x & 1) << 3) + (k & 7);    // tile quad 0..15
  const int brow = tr << 7;
  const int tc0 = tcq << 2;

  const int srow = t >> 2;
  const int scolb = (((t & 3) ^ ((t >> 3) & 3)) << 4);

  int aoff[4], boff[4];
  #pragma unroll
  for (int f = 0; f < 4; ++f) {
    const int ra = wm * 64 + f * 16 + (lane & 15);
    aoff[f] = ra * 64 + (((lane >> 4) * 16) ^ (((ra >> 1) & 3) << 4));
    const int rb = wn * 64 + f * 16 + (lane & 15);
    boff[f] = 8192 + rb * 64 + (((lane >> 4) * 16) ^ (((rb >> 1) & 3) << 4));
  }

  const char* Ab = (const char*)Abf;
  const char* Bb = (const char*)Bbf;
  const float c2 = 2.0f * GAMMA_F * LOG2E_F;

  auto stage = [&](int buf, int kt, int bcol) {
    #pragma unroll
    for (int h = 0; h < 2; ++h) {
      gload_lds16(Ab + (size_t)(brow + h * 64 + srow) * 512 + kt * 64 + scolb,
                  smem + buf * 16384 + h * 4096 + (wid << 10));
      gload_lds16(Bb + (size_t)(bcol + h * 64 + srow) * 512 + kt * 64 + scolb,
                  smem + buf * 16384 + 8192 + h * 4096 + (wid << 10));
    }
  };

  // One fragment (fm,fn) of the parked tile: exp2 + one f32x4 store.
  auto epi_frag = [&](const f32x4 (&pacc)[4][4], int pbcol, int f) {
    const int fm = f >> 2, fn = f & 3;
    const int i = brow + wm * 64 + fm * 16 + (lane & 15);
    const float an = na[i];
    const int j0 = pbcol + wn * 64 + fn * 16 + ((lane >> 4) << 2);
    const f32x4 b4 = *(const f32x4*)&nb[j0];
    f32x4 o;
    o[0] = exp2f(fmaf(c2, pacc[fm][fn][0], an + b4[0]));
    o[1] = exp2f(fmaf(c2, pacc[fm][fn][1], an + b4[1]));
    o[2] = exp2f(fmaf(c2, pacc[fm][fn][2], an + b4[2]));
    o[3] = exp2f(fmaf(c2, pacc[fm][fn][3], an + b4[3]));
    *(f32x4*)(C + (size_t)i * ND + j0) = o;
  };

  f32x4 acc[4][4] = {};
  f32x4 pacc[4][4];

  // ---- prologue: stage global step 0 ----
  stage(0, 0, tc0 << 7);
  __syncthreads();

  #pragma unroll
  for (int t4 = 0; t4 < TPB; ++t4) {
    const int bcol = (tc0 + t4) << 7;
    const int pbcol = (tc0 + t4 - 1) << 7;   // parked tile's col (t4>0)

    #pragma unroll
    for (int kt = 0; kt < NKT; ++kt) {
      const int gs = t4 * NKT + kt;          // global step 0..31
      const int cb = (gs & 1) * 16384;

      short8 af[4], bfv[4];
      #pragma unroll
      for (int f = 0; f < 4; ++f) {
        af[f]  = *(const short8*)(smem + cb + aoff[f]);
        bfv[f] = *(const short8*)(smem + cb + boff[f]);
      }
      const int ns = gs + 1;
      if (ns < TPB * NKT) stage(ns & 1, ns & (NKT - 1), (tc0 + (ns >> 3)) << 7);

      __builtin_amdgcn_s_setprio(1);
      // Swapped operands: thread holds C[i][j0..j0+3].
      #pragma unroll
      for (int fm = 0; fm < 4; ++fm)
        #pragma unroll
        for (int fn = 0; fn < 4; ++fn)
          acc[fm][fn] = __builtin_amdgcn_mfma_f32_16x16x32_bf16(
              bfv[fn], af[fm], acc[fm][fn], 0, 0, 0);
      __builtin_amdgcn_s_setprio(0);

      // ---- pipelined epilogue: 2 fragments of the parked tile ----
      if (t4 > 0) {
        epi_frag(pacc, pbcol, 2 * kt);
        epi_frag(pacc, pbcol, 2 * kt + 1);
      }

      __syncthreads();   // staged loads landed; LDS reads done; stores L2-acked
    }

    // ---- tile boundary: park accumulator, reset ----
    #pragma unroll
    for (int fm = 0; fm < 4; ++fm)
      #pragma unroll
      for (int fn = 0; fn < 4; ++fn) {
        pacc[fm][fn] = acc[fm][fn];
        acc[fm][fn] = (f32x4){0.f, 0.f, 0.f, 0.f};
      }
  }

  // ---- tail: epilogue of the last tile ----
  {
    const int pbcol = (tc0 + TPB - 1) << 7;
    #pragma unroll
    for (int f = 0; f < 16; ++f) epi_frag(pacc, pbcol, f);
  }
}

// ---------------------------------------------------------------------------
// Fallback (tiny d_ws): 128x128 serial kernel, f32->bf16 inline.
// ---------------------------------------------------------------------------
__global__ __launch_bounds__(256) void rbf_gemm_fallback(
    const float* __restrict__ Af, const float* __restrict__ Bf,
    const float* __restrict__ na, const float* __restrict__ nb,
    float* __restrict__ C)
{
  __shared__ __align__(16) char smem[16384];
  const int t = threadIdx.x;
  const int lane = t & 63;
  const int wid = t >> 6;
  const int wm = wid >> 1, wn = wid & 1;
  const int bid = blockIdx.x;
  const int brow = (bid >> 6) << 7;
  const int bcol = (bid & 63) << 7;
  const int srow = t >> 2;
  const int scolb = (((t & 3) ^ ((t >> 3) & 3)) << 4);

  int aoff[4], boff[4];
  #pragma unroll
  for (int f = 0; f < 4; ++f) {
    const int ra = wm * 64 + f * 16 + (lane & 15);
    aoff[f] = ra * 64 + (((lane >> 4) * 16) ^ (((ra >> 1) & 3) << 4));
    const int rb = wn * 64 + f * 16 + (lane & 15);
    boff[f] = 8192 + rb * 64 + (((lane >> 4) * 16) ^ (((rb >> 1) & 3) << 4));
  }

  f32x4 acc[4][4] = {};
  for (int kt = 0; kt < 8; ++kt) {
    #pragma unroll
    for (int h = 0; h < 2; ++h) {
      const float* sa = Af + (size_t)(brow + h * 64 + srow) * KD + kt * 32 + (scolb >> 1);
      const float4 a0 = *(const float4*)sa;
      const float4 a1 = *(const float4*)(sa + 4);
      *(uint4*)(smem + h * 4096 + t * 16) = make_uint4(
          (unsigned)f2b(a0.x) | ((unsigned)f2b(a0.y) << 16),
          (unsigned)f2b(a0.z) | ((unsigned)f2b(a0.w) << 16),
          (unsigned)f2b(a1.x) | ((unsigned)f2b(a1.y) << 16),
          (unsigned)f2b(a1.z) | ((unsigned)f2b(a1.w) << 16));
      const float* sb = Bf + (size_t)(bcol + h * 64 + srow) * KD + kt * 32 + (scolb >> 1);
      const float4 b0 = *(const float4*)sb;
      const float4 b1 = *(const float4*)(sb + 4);
      *(uint4*)(smem + 8192 + h * 4096 + t * 16) = make_uint4(
          (unsigned)f2b(b0.x) | ((unsigned)f2b(b0.y) << 16),
          (unsigned)f2b(b0.z) | ((unsigned)f2b(b0.w) << 16),
          (unsigned)f2b(b1.x) | ((unsigned)f2b(b1.y) << 16),
          (unsigned)f2b(b1.z) | ((unsigned)f2b(b1.w) << 16));
    }
    __syncthreads();
    short8 af[4], bfv[4];
    #pragma unroll
    for (int f = 0; f < 4; ++f) {
      af[f]  = *(const short8*)(smem + aoff[f]);
      bfv[f] = *(const short8*)(smem + boff[f]);
    }
    #pragma unroll
    for (int fm = 0; fm < 4; ++fm)
      #pragma unroll
      for (int fn = 0; fn < 4; ++fn)
        acc[fm][fn] = __builtin_amdgcn_mfma_f32_16x16x32_bf16(
            bfv[fn], af[fm], acc[fm][fn], 0, 0, 0);
    __syncthreads();
  }

  const float c2 = 2.0f * GAMMA_F * LOG2E_F;
  #pragma unroll
  for (int fm = 0; fm < 4; ++fm) {
    const int i = brow + wm * 64 + fm * 16 + (lane & 15);
    const float an = na[i];
    float* crow = C + (size_t)i * ND;
    #pragma unroll
    for (int fn = 0; fn < 4; ++fn) {
      const int j0 = bcol + wn * 64 + fn * 16 + ((lane >> 4) << 2);
      const f32x4 b4 = *(const f32x4*)&nb[j0];
      f32x4 o;
      o[0] = exp2f(fmaf(c2, acc[fm][fn][0], an + b4[0]));
      o[1] = exp2f(fmaf(c2, acc[fm][fn][1], an + b4[1]));
      o[2] = exp2f(fmaf(c2, acc[fm][fn][2], an + b4[2]));
      o[3] = exp2f(fmaf(c2, acc[fm][fn][3], an + b4[3]));
      *(f32x4*)&crow[j0] = o;
    }
  }
}

// ---------------------------------------------------------------------------
extern "C" void kernel_launch(void* const* d_in, const int* in_sizes, int n_in,
                              void* d_out, int out_size, void* d_ws, size_t ws_size,
                              hipStream_t stream) {
  const float* A = (const float*)d_in[0];
  const float* B = (const float*)d_in[1];
  float* C = (float*)d_out;

  const size_t bfBytes = (size_t)ND * KD * 2;   // 4 MiB per matrix
  const size_t normBytes = (size_t)ND * 4;
  char* ws = (char*)d_ws;

  if (ws_size >= 2 * bfBytes + 2 * normBytes) {
    unsigned short* Abf = (unsigned short*)ws;
    unsigned short* Bbf = (unsigned short*)(ws + bfBytes);
    float* na = (float*)(ws + 2 * bfBytes);
    float* nb = (float*)(ws + 2 * bfBytes + normBytes);
    hipLaunchKernelGGL(norm_convert_kernel, dim3(2 * ND / 4), dim3(256), 0, stream,
                       A, B, Abf, Bbf, na, nb);
    hipLaunchKernelGGL(rbf_gemm_kernel, dim3((ND / 128) * (ND / 128) / TPB), dim3(256), 0,
                       stream, Abf, Bbf, na, nb, C);
  } else {
    float* na = (float*)ws;
    float* nb = (float*)(ws + normBytes);
    hipLaunchKernelGGL(norm_convert_kernel, dim3(2 * ND / 4), dim3(256), 0, stream,
                       A, B, (unsigned short*)nullptr, (unsigned short*)nullptr, na, nb);
    hipLaunchKernelGGL(rbf_gemm_fallback, dim3((ND / 128) * (ND / 128)), dim3(256), 0,
                       stream, A, B, na, nb, C);
  }
}

// Round 13
// 84.026 us; speedup vs baseline: 2.2316x; 1.0191x over previous
//
#include <hip/hip_runtime.h>
#include <hip/hip_bf16.h>
#include <cstdint>
#include <cstddef>

// RBF Gram matrix: K[i,j] = exp(-gamma * ||a_i - b_j||^2), A,B: [8192,256] f32.
// Out: [8192,8192] f32.
//
// Round-13: R11 base (counted-vmcnt triple-buffer, 3 blocks/CU, involution
// staging w/ 0 bank conflicts, swapped-operand MFMA, XCD 16x32 regions)
// with a lean epilogue: raw v_exp_f32 (args provably in [-8,0] -> no libm
// fixups needed), packed f32 adds/fmas via f32x4 vector ops, nb fragment
// loads hoisted 16 -> 4. Epilogue VALU roughly halves. R10/R11/R12 all at
// ~85.7: schedule permutations exhausted; cutting serial-chain work terms.

#define GAMMA_F 0.00390625f
#define LOG2E_F 1.44269504088896340736f

typedef __attribute__((ext_vector_type(8))) short short8;   // 8 bf16
typedef __attribute__((ext_vector_type(4))) float f32x4;    // acc / 16B

constexpr int KD = 256;
constexpr int ND = 8192;
constexpr int NKT = KD / 32;   // 8 K-steps of BK=32

__device__ __forceinline__ unsigned short f2b(float f) {
  unsigned int u = __float_as_uint(f);
  u += 0x7FFFu + ((u >> 16) & 1u);
  return (unsigned short)(u >> 16);
}

// Raw v_exp_f32: exact for our arg range [-8, 0] (all results normal).
__device__ __forceinline__ float fast_exp2(float x) {
#if __has_builtin(__builtin_amdgcn_exp2f)
  return __builtin_amdgcn_exp2f(x);
#else
  float r;
  asm volatile("v_exp_f32 %0, %1\n\ts_nop 1" : "=v"(r) : "v"(x));
  return r;
#endif
}

__device__ __forceinline__ void gload_lds16(const void* g, void* l) {
  __builtin_amdgcn_global_load_lds(
      (const __attribute__((address_space(1))) unsigned int*)g,
      (__attribute__((address_space(3))) unsigned int*)l, 16, 0, 0);
}

#define FULL_BARRIER() do { asm volatile("" ::: "memory"); \
  __builtin_amdgcn_s_barrier(); asm volatile("" ::: "memory"); } while (0)

// ---------------------------------------------------------------------------
// Prepass: pre-scaled row norms n = -gamma*log2e*||row||^2 + bf16 convert.
// ---------------------------------------------------------------------------
__global__ __launch_bounds__(256) void norm_convert_kernel(
    const float* __restrict__ A, const float* __restrict__ B,
    unsigned short* Abf, unsigned short* Bbf,
    float* __restrict__ na, float* __restrict__ nb)
{
  const int lane = threadIdx.x & 63;
  const int row = blockIdx.x * 4 + (threadIdx.x >> 6);
  const float* src = A;
  unsigned short* dst = Abf;
  float* nrm = na;
  int r = row;
  if (row >= ND) { src = B; dst = Bbf; nrm = nb; r = row - ND; }

  const float4 v = *(const float4*)(src + (size_t)r * KD + lane * 4);
  float s = v.x * v.x + v.y * v.y + v.z * v.z + v.w * v.w;
  #pragma unroll
  for (int off = 32; off >= 1; off >>= 1) s += __shfl_xor(s, off, 64);

  if (dst) {
    const unsigned int p0 = (unsigned)f2b(v.x) | ((unsigned)f2b(v.y) << 16);
    const unsigned int p1 = (unsigned)f2b(v.z) | ((unsigned)f2b(v.w) << 16);
    *(uint2*)(dst + (size_t)r * KD + lane * 4) = make_uint2(p0, p1);
  }
  if (lane == 0) nrm[r] = -GAMMA_F * LOG2E_F * s;
}

// ---------------------------------------------------------------------------
// Main 128x128 GEMM + RBF epilogue. 256 threads = 4 waves (2x2); wave owns
// 64x64 (acc[4][4]). LDS: 3 bufs x 16KB = 48KB -> 3 blocks/CU.
//
// Pipeline (T4): step k reads buf k%3, stages step k+2 into buf (k+2)%3,
// boundary waits vmcnt(4); vmcnt never drains to 0 in the steady loop.
// ---------------------------------------------------------------------------
__global__ __launch_bounds__(256, 3) void rbf_gemm_kernel(
    const unsigned short* __restrict__ Abf, const unsigned short* __restrict__ Bbf,
    const float* __restrict__ na, const float* __restrict__ nb,
    float* __restrict__ C)
{
  __shared__ __align__(16) char smem[49152];
  const int t = threadIdx.x;
  const int lane = t & 63;
  const int wid = t >> 6;
  const int wm = wid >> 1, wn = wid & 1;

  // XCD mapping (bijective, 8 XCDs x 512): 16x32-tile region per XCD.
  const int bid = blockIdx.x;
  const int x = bid & 7;
  const int k = bid >> 3;
  const int tr = ((x >> 1) << 4) + (k >> 5);   // tile row 0..63
  const int tc = ((x & 1) << 5) + (k & 31);    // tile col 0..63
  const int brow = tr << 7;
  const int bcol = tc << 7;

  // Staging: linear dest chunk + t*16; GLOBAL source col swizzled by the
  // involution f(b)=b^(((b>>7)&3)<<4) -> scolb = ((t&3)^((t>>3)&3))<<4.
  const int srow = t >> 2;                                   // 0..63
  const int scolb = (((t & 3) ^ ((t >> 3) & 3)) << 4);

  // Fragment ds_read offsets (within buf; add buf*16384 at use).
  int aoff[4], boff[4];
  #pragma unroll
  for (int f = 0; f < 4; ++f) {
    const int ra = wm * 64 + f * 16 + (lane & 15);
    aoff[f] = ra * 64 + (((lane >> 4) * 16) ^ (((ra >> 1) & 3) << 4));
    const int rb = wn * 64 + f * 16 + (lane & 15);
    boff[f] = 8192 + rb * 64 + (((lane >> 4) * 16) ^ (((rb >> 1) & 3) << 4));
  }

  const char* Ab = (const char*)Abf;
  const char* Bb = (const char*)Bbf;

  auto stage = [&](int buf, int kt) {
    #pragma unroll
    for (int h = 0; h < 2; ++h) {
      gload_lds16(Ab + (size_t)(brow + h * 64 + srow) * 512 + kt * 64 + scolb,
                  smem + buf * 16384 + h * 4096 + (wid << 10));
      gload_lds16(Bb + (size_t)(bcol + h * 64 + srow) * 512 + kt * 64 + scolb,
                  smem + buf * 16384 + 8192 + h * 4096 + (wid << 10));
    }
  };

  f32x4 acc[4][4] = {};

  // ---- prologue: 2 steps staged; wait only for step 0 ----
  stage(0, 0);
  stage(1, 1);
  asm volatile("s_waitcnt vmcnt(4)" ::: "memory");
  FULL_BARRIER();

  #pragma unroll
  for (int kt = 0; kt < NKT; ++kt) {
    const int cb = (kt % 3) * 16384;

    short8 af[4], bfv[4];
    #pragma unroll
    for (int f = 0; f < 4; ++f) {
      af[f]  = *(const short8*)(smem + cb + aoff[f]);
      bfv[f] = *(const short8*)(smem + cb + boff[f]);
    }
    if (kt + 2 < NKT) stage((kt + 2) % 3, kt + 2);

    __builtin_amdgcn_s_setprio(1);
    // Swapped operands: thread holds C[i][j0..j0+3].
    #pragma unroll
    for (int fm = 0; fm < 4; ++fm)
      #pragma unroll
      for (int fn = 0; fn < 4; ++fn)
        acc[fm][fn] = __builtin_amdgcn_mfma_f32_16x16x32_bf16(
            bfv[fn], af[fm], acc[fm][fn], 0, 0, 0);
    __builtin_amdgcn_s_setprio(0);

    if (kt < NKT - 1) {
      if (kt + 2 < NKT) { asm volatile("s_waitcnt vmcnt(4)" ::: "memory"); }
      else              { asm volatile("s_waitcnt vmcnt(0)" ::: "memory"); }
      FULL_BARRIER();
    }
  }

  // ---- lean epilogue: K = exp2(na + nb + 2*gamma*log2e*dot) ----
  // b4s hoisted (fm-invariant); f32x4 vector math -> v_pk_add/pk_fma;
  // raw v_exp_f32 (args in [-8,0], no fixups needed).
  const float c2 = 2.0f * GAMMA_F * LOG2E_F;
  f32x4 b4s[4];
  #pragma unroll
  for (int fn = 0; fn < 4; ++fn) {
    const int j0 = bcol + wn * 64 + fn * 16 + ((lane >> 4) << 2);
    b4s[fn] = *(const f32x4*)&nb[j0];
  }
  #pragma unroll
  for (int fm = 0; fm < 4; ++fm) {
    const int i = brow + wm * 64 + fm * 16 + (lane & 15);
    const float an = na[i];
    float* crow = C + (size_t)i * ND;
    #pragma unroll
    for (int fn = 0; fn < 4; ++fn) {
      const int j0 = bcol + wn * 64 + fn * 16 + ((lane >> 4) << 2);
      f32x4 arg = b4s[fn] + an;          // v_pk_add_f32 x2
      arg = acc[fm][fn] * c2 + arg;      // v_pk_fma_f32 x2
      f32x4 o;
      o[0] = fast_exp2(arg[0]);
      o[1] = fast_exp2(arg[1]);
      o[2] = fast_exp2(arg[2]);
      o[3] = fast_exp2(arg[3]);
      *(f32x4*)&crow[j0] = o;
    }
  }
}

// ---------------------------------------------------------------------------
// Fallback (tiny d_ws): 128x128 serial kernel, f32->bf16 inline.
// ---------------------------------------------------------------------------
__global__ __launch_bounds__(256) void rbf_gemm_fallback(
    const float* __restrict__ Af, const float* __restrict__ Bf,
    const float* __restrict__ na, const float* __restrict__ nb,
    float* __restrict__ C)
{
  __shared__ __align__(16) char smem[16384];
  const int t = threadIdx.x;
  const int lane = t & 63;
  const int wid = t >> 6;
  const int wm = wid >> 1, wn = wid & 1;
  const int bid = blockIdx.x;
  const int brow = (bid >> 6) << 7;
  const int bcol = (bid & 63) << 7;
  const int srow = t >> 2;
  const int scolb = (((t & 3) ^ ((t >> 3) & 3)) << 4);

  int aoff[4], boff[4];
  #pragma unroll
  for (int f = 0; f < 4; ++f) {
    const int ra = wm * 64 + f * 16 + (lane & 15);
    aoff[f] = ra * 64 + (((lane >> 4) * 16) ^ (((ra >> 1) & 3) << 4));
    const int rb = wn * 64 + f * 16 + (lane & 15);
    boff[f] = 8192 + rb * 64 + (((lane >> 4) * 16) ^ (((rb >> 1) & 3) << 4));
  }

  f32x4 acc[4][4] = {};
  for (int kt = 0; kt < 8; ++kt) {
    #pragma unroll
    for (int h = 0; h < 2; ++h) {
      const float* sa = Af + (size_t)(brow + h * 64 + srow) * KD + kt * 32 + (scolb >> 1);
      const float4 a0 = *(const float4*)sa;
      const float4 a1 = *(const float4*)(sa + 4);
      *(uint4*)(smem + h * 4096 + t * 16) = make_uint4(
          (unsigned)f2b(a0.x) | ((unsigned)f2b(a0.y) << 16),
          (unsigned)f2b(a0.z) | ((unsigned)f2b(a0.w) << 16),
          (unsigned)f2b(a1.x) | ((unsigned)f2b(a1.y) << 16),
          (unsigned)f2b(a1.z) | ((unsigned)f2b(a1.w) << 16));
      const float* sb = Bf + (size_t)(bcol + h * 64 + srow) * KD + kt * 32 + (scolb >> 1);
      const float4 b0 = *(const float4*)sb;
      const float4 b1 = *(const float4*)(sb + 4);
      *(uint4*)(smem + 8192 + h * 4096 + t * 16) = make_uint4(
          (unsigned)f2b(b0.x) | ((unsigned)f2b(b0.y) << 16),
          (unsigned)f2b(b0.z) | ((unsigned)f2b(b0.w) << 16),
          (unsigned)f2b(b1.x) | ((unsigned)f2b(b1.y) << 16),
          (unsigned)f2b(b1.z) | ((unsigned)f2b(b1.w) << 16));
    }
    __syncthreads();
    short8 af[4], bfv[4];
    #pragma unroll
    for (int f = 0; f < 4; ++f) {
      af[f]  = *(const short8*)(smem + aoff[f]);
      bfv[f] = *(const short8*)(smem + boff[f]);
    }
    #pragma unroll
    for (int fm = 0; fm < 4; ++fm)
      #pragma unroll
      for (int fn = 0; fn < 4; ++fn)
        acc[fm][fn] = __builtin_amdgcn_mfma_f32_16x16x32_bf16(
            bfv[fn], af[fm], acc[fm][fn], 0, 0, 0);
    __syncthreads();
  }

  const float c2 = 2.0f * GAMMA_F * LOG2E_F;
  #pragma unroll
  for (int fm = 0; fm < 4; ++fm) {
    const int i = brow + wm * 64 + fm * 16 + (lane & 15);
    const float an = na[i];
    float* crow = C + (size_t)i * ND;
    #pragma unroll
    for (int fn = 0; fn < 4; ++fn) {
      const int j0 = bcol + wn * 64 + fn * 16 + ((lane >> 4) << 2);
      const f32x4 b4 = *(const f32x4*)&nb[j0];
      f32x4 arg = b4 + an;
      arg = acc[fm][fn] * c2 + arg;
      f32x4 o;
      o[0] = fast_exp2(arg[0]);
      o[1] = fast_exp2(arg[1]);
      o[2] = fast_exp2(arg[2]);
      o[3] = fast_exp2(arg[3]);
      *(f32x4*)&crow[j0] = o;
    }
  }
}

// ---------------------------------------------------------------------------
extern "C" void kernel_launch(void* const* d_in, const int* in_sizes, int n_in,
                              void* d_out, int out_size, void* d_ws, size_t ws_size,
                              hipStream_t stream) {
  const float* A = (const float*)d_in[0];
  const float* B = (const float*)d_in[1];
  float* C = (float*)d_out;

  const size_t bfBytes = (size_t)ND * KD * 2;   // 4 MiB per matrix
  const size_t normBytes = (size_t)ND * 4;
  char* ws = (char*)d_ws;

  if (ws_size >= 2 * bfBytes + 2 * normBytes) {
    unsigned short* Abf = (unsigned short*)ws;
    unsigned short* Bbf = (unsigned short*)(ws + bfBytes);
    float* na = (float*)(ws + 2 * bfBytes);
    float* nb = (float*)(ws + 2 * bfBytes + normBytes);
    hipLaunchKernelGGL(norm_convert_kernel, dim3(2 * ND / 4), dim3(256), 0, stream,
                       A, B, Abf, Bbf, na, nb);
    hipLaunchKernelGGL(rbf_gemm_kernel, dim3((ND / 128) * (ND / 128)), dim3(256), 0,
                       stream, Abf, Bbf, na, nb, C);
  } else {
    float* na = (float*)ws;
    float* nb = (float*)(ws + normBytes);
    hipLaunchKernelGGL(norm_convert_kernel, dim3(2 * ND / 4), dim3(256), 0, stream,
                       A, B, (unsigned short*)nullptr, (unsigned short*)nullptr, na, nb);
    hipLaunchKernelGGL(rbf_gemm_fallback, dim3((ND / 128) * (ND / 128)), dim3(256), 0,
                       stream, A, B, na, nb, C);
  }
}